// Round 4
// baseline (4507.496 us; speedup 1.0000x reference)
//
#include <hip/hip_runtime.h>

// LSTM persistent-RNN kernel for MI355X (gfx950).
// B=64, T=512, D=1024, H=1024. out[t][b][h] fp32.
//
// Round 4: t-indexed h history buffer (write-once addresses) -> consumer h
// loads are plain L2-cached loads (16x less LLC traffic, ~200cyc L2 hits
// instead of ~700cyc LLC). Per-wave partial barrier: wave w polls only its
// 32 producer blocks (K-slice ownership), no block-wide sync on the
// consume side.

typedef short short8 __attribute__((ext_vector_type(8)));
typedef float f32x4 __attribute__((ext_vector_type(4)));

#define NBLK 128
#define TPB 256

__device__ __forceinline__ unsigned bfbits(float f) {
  unsigned u = __float_as_uint(f);
  return ((u + 0x7fffu + ((u >> 16) & 1u)) >> 16) & 0xffffu;  // RNE
}

__device__ __forceinline__ short8 cvt8(const float* p) {
  const float4* q = (const float4*)p;
  float4 a = q[0], b = q[1];
  short8 r;
  r[0] = (short)bfbits(a.x); r[1] = (short)bfbits(a.y);
  r[2] = (short)bfbits(a.z); r[3] = (short)bfbits(a.w);
  r[4] = (short)bfbits(b.x); r[5] = (short)bfbits(b.y);
  r[6] = (short)bfbits(b.z); r[7] = (short)bfbits(b.w);
  return r;
}

__device__ __forceinline__ float sigmoidf_(float x) {
  return 1.0f / (1.0f + __expf(-x));
}
__device__ __forceinline__ float tanhf_(float x) {
  float ax = fabsf(x);
  float e = __expf(-2.0f * ax);  // in (0,1], never overflows
  float r = (1.0f - e) / (1.0f + e);
  return copysignf(r, x);
}

__global__ void cvt_x_kernel(const float* __restrict__ x,
                             unsigned short* __restrict__ xb, int n4) {
  int i = blockIdx.x * blockDim.x + threadIdx.x;
  int stride = gridDim.x * blockDim.x;
  const float4* xv = (const float4*)x;
  uint2* ov = (uint2*)xb;
  for (; i < n4; i += stride) {
    float4 v = xv[i];
    uint2 o;
    o.x = bfbits(v.x) | (bfbits(v.y) << 16);
    o.y = bfbits(v.z) | (bfbits(v.w) << 16);
    ov[i] = o;
  }
}

// Gate order: 0=i, 1=f, 2=o, 3=c(g). Block bid owns hidden units
// [bid*8, bid*8+8). Its 32 gate-columns: col c = 8*g + u.
// MFMA 16x16x32 bf16. A-frag: lane l -> row l&15, k = 8*(l>>4)+j.
// B-frag: lane l -> col l&15, k = 8*(l>>4)+j. C/D: col=l&15,
// row=(l>>4)*4+reg (HW-verified per guide m89/m91).
//
// hist layout: slot s (s=0..T) holds h_state after step s-1; slot 0 = zeros.
// Step t reads slot t (gated by flags >= t+1), writes slot t+1, then sets
// flag = t+2. Addresses are write-once -> plain cached loads are safe.
__global__ __launch_bounds__(TPB, 1) void lstm_persist(
    const float* __restrict__ x, const unsigned short* __restrict__ xb,
    const float* __restrict__ Wi, const float* __restrict__ Wf,
    const float* __restrict__ Wo, const float* __restrict__ Wc,
    const float* __restrict__ bi, const float* __restrict__ bfv,
    const float* __restrict__ bo, const float* __restrict__ bc,
    unsigned short* __restrict__ hist, unsigned* __restrict__ flags,
    float* __restrict__ out) {
  constexpr int B = 64, T = 512, D = 1024, H = 1024;
  const int tid = threadIdx.x;
  const int bid = blockIdx.x;
  const int lane = tid & 63;
  const int w = tid >> 6;    // wave 0..3 -> K-slice [256w, 256w+256)
  const int cl = lane & 15;
  const int kg = lane >> 4;  // k-group within fragment
  const int j0 = bid * 8;

  // One-time: make any pre-dispatch remote writes visible / drop stale lines.
  __builtin_amdgcn_fence(__ATOMIC_ACQUIRE, "agent");

  __shared__ float part[4][32][68];  // [wave][col][row+pad] fp32 partials

  // ---- Load weight fragments into registers (once) ----
  const float* Wg[4] = {Wi, Wf, Wo, Wc};
  short8 bxw[2][8], bhw[2][8];
#pragma unroll
  for (int nt = 0; nt < 2; ++nt) {
    int g = 2 * nt + (cl >> 3);
    const float* wrow = Wg[g] + (size_t)(j0 + (cl & 7)) * 2048;
#pragma unroll
    for (int kf = 0; kf < 8; ++kf) {
      int kx = 256 * w + 32 * kf + 8 * kg;
      bxw[nt][kf] = cvt8(wrow + kx);         // x-part columns [0,1024)
      bhw[nt][kf] = cvt8(wrow + 1024 + kx);  // h-part columns [1024,2048)
    }
  }

  // ---- Activation-stage assignment: thread -> (row, unit-pair) ----
  const int row = tid >> 2;  // batch row 0..63
  const int up = tid & 3;    // unit pair: units 2*up, 2*up+1
  float biasv[4][2];
#pragma unroll
  for (int k = 0; k < 2; ++k) {
    biasv[0][k] = bi[j0 + 2 * up + k];
    biasv[1][k] = bfv[j0 + 2 * up + k];
    biasv[2][k] = bo[j0 + 2 * up + k];
    biasv[3][k] = bc[j0 + 2 * up + k];
  }
  float cst[2] = {0.0f, 0.0f};  // cell state (registers, persistent)

  const int kxbase = 256 * w + 8 * kg;

  // ---- Zero hist slot 0 (coherent write-through), then arrive ----
  unsigned* hz = (unsigned*)hist;
  __hip_atomic_store(&hz[bid * TPB + tid], 0u, __ATOMIC_RELAXED,
                     __HIP_MEMORY_SCOPE_AGENT);
  __syncthreads();  // drains the coherent stores before flagging
  if (tid == 0)
    __hip_atomic_store(&flags[bid * 32], 1u, __ATOMIC_RELAXED,
                       __HIP_MEMORY_SCOPE_AGENT);

  for (int t = 0; t < T; ++t) {
    const unsigned short* hprev = hist + (size_t)t * 65536;
    unsigned short* hnext = hist + (size_t)(t + 1) * 65536;

    f32x4 acc[4][2];
#pragma unroll
    for (int mt = 0; mt < 4; ++mt)
#pragma unroll
      for (int nt = 0; nt < 2; ++nt) acc[mt][nt] = (f32x4)0.0f;

    // ---- x-part MFMAs (independent of h -> before the barrier wait) ----
#pragma unroll
    for (int kf = 0; kf < 8; ++kf) {
      int kx = kxbase + 32 * kf;
      short8 af[4];
      if (xb) {
#pragma unroll
        for (int mt = 0; mt < 4; ++mt) {
          int b = 16 * mt + cl;
          af[mt] = *(const short8*)(xb + ((size_t)b * T + t) * D + kx);
        }
      } else {
#pragma unroll
        for (int mt = 0; mt < 4; ++mt) {
          int b = 16 * mt + cl;
          af[mt] = cvt8(x + ((size_t)b * T + t) * D + kx);
        }
      }
#pragma unroll
      for (int mt = 0; mt < 4; ++mt) {
        acc[mt][0] = __builtin_amdgcn_mfma_f32_16x16x32_bf16(
            af[mt], bxw[0][kf], acc[mt][0], 0, 0, 0);
        acc[mt][1] = __builtin_amdgcn_mfma_f32_16x16x32_bf16(
            af[mt], bxw[1][kf], acc[mt][1], 0, 0, 0);
      }
    }

    // ---- Per-wave partial barrier: wave w's K-slice [256w, 256w+256) is
    // produced exactly by blocks [32w, 32w+32). Poll only those 32 flags.
    {
      const unsigned target = (unsigned)(t + 1);
      const unsigned* fp = flags + (size_t)(32 * w + (lane & 31)) * 32;
      while (true) {
        unsigned v =
            __hip_atomic_load(fp, __ATOMIC_RELAXED, __HIP_MEMORY_SCOPE_AGENT);
        if (__all((int)(v >= target))) break;
        __builtin_amdgcn_s_sleep(1);
      }
    }
    asm volatile("" ::: "memory");  // no h-loads hoisted above the poll

    // ---- h-part: plain cached loads (write-once addresses -> never stale;
    // same-XCD blocks MSHR-coalesce onto one LLC fetch per line) ----
    short8 ah[8][4];
#pragma unroll
    for (int kf = 0; kf < 8; ++kf) {
      int kh = kxbase + 32 * kf;
#pragma unroll
      for (int mt = 0; mt < 4; ++mt)
        ah[kf][mt] = *(const short8*)(hprev + (size_t)(16 * mt + cl) * H + kh);
    }
#pragma unroll
    for (int kf = 0; kf < 8; ++kf) {
#pragma unroll
      for (int mt = 0; mt < 4; ++mt) {
        acc[mt][0] = __builtin_amdgcn_mfma_f32_16x16x32_bf16(
            ah[kf][mt], bhw[0][kf], acc[mt][0], 0, 0, 0);
        acc[mt][1] = __builtin_amdgcn_mfma_f32_16x16x32_bf16(
            ah[kf][mt], bhw[1][kf], acc[mt][1], 0, 0, 0);
      }
    }

    // ---- Cross-wave reduce via LDS ----
#pragma unroll
    for (int mt = 0; mt < 4; ++mt)
#pragma unroll
      for (int nt = 0; nt < 2; ++nt)
        *(f32x4*)&part[w][16 * nt + cl][16 * mt + 4 * kg] = acc[mt][nt];
    __syncthreads();

    // ---- Activations + cell update: thread -> (row, units 2up..2up+1) ----
    float hv[2];
#pragma unroll
    for (int k = 0; k < 2; ++k) {
      int u = 2 * up + k;
      float pre[4];
#pragma unroll
      for (int g = 0; g < 4; ++g) {
        float s = biasv[g][k];
#pragma unroll
        for (int ww = 0; ww < 4; ++ww) s += part[ww][8 * g + u][row];
        pre[g] = s;
      }
      float iv = sigmoidf_(pre[0]);
      float fv = sigmoidf_(pre[1]);
      float ov = sigmoidf_(pre[2]);
      float gv = tanhf_(pre[3]);
      cst[k] = fv * cst[k] + iv * gv;
      hv[k] = ov * tanhf_(cst[k]);
    }
    // packed coherent h store (1 dword) -- the only store that must drain
    unsigned hpack = bfbits(hv[0]) | (bfbits(hv[1]) << 16);
    __hip_atomic_store((unsigned*)(hnext + (size_t)row * H + j0 + 2 * up),
                       hpack, __ATOMIC_RELAXED, __HIP_MEMORY_SCOPE_AGENT);

    // ---- Publish h_t: drain h stores, then arrive (plain flag store) ----
    __syncthreads();
    asm volatile("" ::: "memory");
    if (tid == 0)
      __hip_atomic_store(&flags[bid * 32], (unsigned)(t + 2), __ATOMIC_RELAXED,
                         __HIP_MEMORY_SCOPE_AGENT);

    // ---- out store AFTER arrive: drains during next step's poll ----
    float* op = out + ((size_t)t * B + row) * H + j0 + 2 * up;
    __builtin_nontemporal_store(hv[0], op);
    __builtin_nontemporal_store(hv[1], op + 1);
  }
}

extern "C" void kernel_launch(void* const* d_in, const int* in_sizes, int n_in,
                              void* d_out, int out_size, void* d_ws,
                              size_t ws_size, hipStream_t stream) {
  const float* x = (const float*)d_in[0];
  const float* Wi = (const float*)d_in[1];
  const float* bi = (const float*)d_in[2];
  const float* Wf = (const float*)d_in[3];
  const float* bfv = (const float*)d_in[4];
  const float* Wo = (const float*)d_in[5];
  const float* bo = (const float*)d_in[6];
  const float* Wc = (const float*)d_in[7];
  const float* bc = (const float*)d_in[8];
  float* out = (float*)d_out;

  char* ws = (char*)d_ws;
  const size_t xb_bytes = (size_t)64 * 512 * 1024 * 2;        // 64 MiB bf16 x
  const size_t hist_bytes = (size_t)513 * 64 * 1024 * 2;      // 64.1 MiB hist
  const size_t fl_bytes = (size_t)NBLK * 32 * 4;              // flag array

  unsigned short* xb = nullptr;
  size_t off = 0;
  if (ws_size >= xb_bytes + hist_bytes + fl_bytes) {
    xb = (unsigned short*)ws;
    off = xb_bytes;
  }
  unsigned short* hist = (unsigned short*)(ws + off);
  off += hist_bytes;
  unsigned* flags = (unsigned*)(ws + off);

  hipMemsetAsync(flags, 0, fl_bytes, stream);
  if (xb) cvt_x_kernel<<<2048, 256, 0, stream>>>(x, xb, (64 * 512 * 1024) / 4);
  lstm_persist<<<NBLK, TPB, 0, stream>>>(x, xb, Wi, Wf, Wo, Wc, bi, bfv, bo, bc,
                                         hist, flags, out);
}